// Round 1
// 832.832 us; speedup vs baseline: 1.2456x; 1.2456x over previous
//
#include <hip/hip_runtime.h>

typedef _Float16 f16;
typedef _Float16 f16x8 __attribute__((ext_vector_type(8)));
typedef float f32x4 __attribute__((ext_vector_type(4)));

#define BS 65536
#define D 768
#define H 12
#define BM 128
// B tile: 192 W-rows (q 0-63 | k 64-127 | v 128-191) x 64 k, f16, double-buffered.
// XOR swizzle: 16B chunk c of row n lives at byte n*128 + (c ^ (n&7))*16.
#define SB_ELEMS (192 * 64)

// Grid: BS/BM = 512 blocks. Block: 512 threads = 8 waves, wave w owns rows w*16..w*16+15.
// LN once per block -> A frags in registers (a[24] f16x8 covers K=768).
// Loop heads inside the block: B reg-staged (f32->f16) into swizzled LDS dbuf,
// issue-early/write-late, ONE barrier per K-step. Attention epilogue fully in-register.
__global__ __launch_bounds__(512, 2) void fused_kernel(
    const float* __restrict__ x,
    const float* __restrict__ Wq, const float* __restrict__ Wk,
    const float* __restrict__ Wv,
    const float* __restrict__ gamma, const float* __restrict__ beta,
    float* __restrict__ out) {
  __shared__ f16 sB[2][SB_ELEMS] __attribute__((aligned(16)));

  const int tid  = threadIdx.x;
  const int wave = tid >> 6;
  const int lane = tid & 63;
  const int m    = lane & 15;   // MFMA lane-col
  const int qg   = lane >> 4;   // k-octet / row-quad group

  // ---- staging role: every thread stages row nn of each of Wq/Wk/Wv, k-chunk cc ----
  const int nn  = tid >> 3;                    // 0..63
  const int cc  = tid & 7;                     // 0..7 (8 f16 = 16B chunk)
  const int swc = (cc ^ (nn & 7)) * 8;         // swizzled chunk offset (f16 elems)
  const size_t sbase = (size_t)nn * D + cc * 8;

  float4 wl0, wl1, wl2, wl3, wl4, wl5;

  auto issue = [&](int hh, int koo) {
    size_t off = (size_t)hh * (64 * D) + sbase + (size_t)(koo * 64);
    wl0 = *(const float4*)(Wq + off); wl1 = *(const float4*)(Wq + off + 4);
    wl2 = *(const float4*)(Wk + off); wl3 = *(const float4*)(Wk + off + 4);
    wl4 = *(const float4*)(Wv + off); wl5 = *(const float4*)(Wv + off + 4);
  };
  auto commit = [&](int nxt) {
    f16* dst = &sB[nxt][0];
    f16x8 t0, t1, t2;
    t0[0]=(f16)wl0.x; t0[1]=(f16)wl0.y; t0[2]=(f16)wl0.z; t0[3]=(f16)wl0.w;
    t0[4]=(f16)wl1.x; t0[5]=(f16)wl1.y; t0[6]=(f16)wl1.z; t0[7]=(f16)wl1.w;
    t1[0]=(f16)wl2.x; t1[1]=(f16)wl2.y; t1[2]=(f16)wl2.z; t1[3]=(f16)wl2.w;
    t1[4]=(f16)wl3.x; t1[5]=(f16)wl3.y; t1[6]=(f16)wl3.z; t1[7]=(f16)wl3.w;
    t2[0]=(f16)wl4.x; t2[1]=(f16)wl4.y; t2[2]=(f16)wl4.z; t2[3]=(f16)wl4.w;
    t2[4]=(f16)wl5.x; t2[5]=(f16)wl5.y; t2[6]=(f16)wl5.z; t2[7]=(f16)wl5.w;
    *(f16x8*)(dst + (size_t)nn * 64 + swc)        = t0;
    *(f16x8*)(dst + (size_t)(64 + nn) * 64 + swc)  = t1;
    *(f16x8*)(dst + (size_t)(128 + nn) * 64 + swc) = t2;
  };

  // A-row for this lane (LN + MFMA A-frag): row = blk*128 + wave*16 + m
  const size_t arow = (size_t)blockIdx.x * BM + wave * 16 + m;

  // issue W(h=0,ko=0) first so its latency hides under the LN phase
  issue(0, 0);

  // ---- LayerNorm once, A fragments straight into registers ----
  f16x8 a[24];  // a[s]: k = s*32 + qg*8 .. +8 (raw x first, normalized in place)
  {
    const float* xr = x + arow * D + qg * 8;
    float sum = 0.f, sq = 0.f;
#pragma unroll
    for (int s = 0; s < 24; ++s) {
      float4 x0 = *(const float4*)(xr + s * 32);
      float4 x1 = *(const float4*)(xr + s * 32 + 4);
      sum += x0.x + x0.y + x0.z + x0.w + x1.x + x1.y + x1.z + x1.w;
      sq  += x0.x*x0.x + x0.y*x0.y + x0.z*x0.z + x0.w*x0.w
           + x1.x*x1.x + x1.y*x1.y + x1.z*x1.z + x1.w*x1.w;
      f16x8 t;
      t[0]=(f16)x0.x; t[1]=(f16)x0.y; t[2]=(f16)x0.z; t[3]=(f16)x0.w;
      t[4]=(f16)x1.x; t[5]=(f16)x1.y; t[6]=(f16)x1.z; t[7]=(f16)x1.w;
      a[s] = t;
    }
    // lanes {l, l^16, l^32, l^48} hold disjoint quarters of the same row
    sum += __shfl_xor(sum, 16, 64); sum += __shfl_xor(sum, 32, 64);
    sq  += __shfl_xor(sq, 16, 64);  sq  += __shfl_xor(sq, 32, 64);
    float mu   = sum * (1.0f / D);
    float rstd = rsqrtf(sq * (1.0f / D) - mu * mu + 1e-6f);
    const float* gp = gamma + qg * 8;
    const float* bp = beta + qg * 8;
#pragma unroll
    for (int s = 0; s < 24; ++s) {
      float4 g0 = *(const float4*)(gp + s * 32);
      float4 g1 = *(const float4*)(gp + s * 32 + 4);
      float4 b0 = *(const float4*)(bp + s * 32);
      float4 b1 = *(const float4*)(bp + s * 32 + 4);
      f16x8 v = a[s];
      f16x8 t;
      t[0] = (f16)(((float)v[0] - mu) * rstd * g0.x + b0.x);
      t[1] = (f16)(((float)v[1] - mu) * rstd * g0.y + b0.y);
      t[2] = (f16)(((float)v[2] - mu) * rstd * g0.z + b0.z);
      t[3] = (f16)(((float)v[3] - mu) * rstd * g0.w + b0.w);
      t[4] = (f16)(((float)v[4] - mu) * rstd * g1.x + b1.x);
      t[5] = (f16)(((float)v[5] - mu) * rstd * g1.y + b1.y);
      t[6] = (f16)(((float)v[6] - mu) * rstd * g1.z + b1.z);
      t[7] = (f16)(((float)v[7] - mu) * rstd * g1.w + b1.w);
      a[s] = t;
    }
  }

  commit(0);
  __syncthreads();

  // B-frag read offsets (swizzled): row n = t*16+m -> n&7 == m&7
  const int boff0 = m * 64 + ((qg ^ (m & 7)) * 8);  // k-slice s=0
  const int boff1 = boff0 ^ 32;                     // k-slice s=1 (chunk ^ 4)

  for (int h = 0; h < H; ++h) {
    f32x4 acc[12];
#pragma unroll
    for (int t = 0; t < 12; ++t) acc[t] = (f32x4){0.f, 0.f, 0.f, 0.f};

#pragma unroll
    for (int ko = 0; ko < 12; ++ko) {
      const int cur = ko & 1;  // compile-time: 12 even -> parity independent of h
      // issue next chunk's global loads before compute (T14 issue-early)
      if (ko < 11) {
        issue(h, ko + 1);
      } else if (h < H - 1) {
        issue(h + 1, 0);
      }

      const f16* bb = &sB[cur][0];
#pragma unroll
      for (int t = 0; t < 12; ++t) {
        f16x8 b0 = *(const f16x8*)(bb + t * 1024 + boff0);
        f16x8 b1 = *(const f16x8*)(bb + t * 1024 + boff1);
        acc[t] = __builtin_amdgcn_mfma_f32_16x16x32_f16(a[2 * ko],     b0, acc[t], 0, 0, 0);
        acc[t] = __builtin_amdgcn_mfma_f32_16x16x32_f16(a[2 * ko + 1], b1, acc[t], 0, 0, 0);
      }
      // keep the vmcnt-wait + LDS write of the NEXT buffer after the MFMAs
      __builtin_amdgcn_sched_barrier(0);
      if (ko < 11) {
        commit(cur ^ 1);
        __syncthreads();
      } else if (h < H - 1) {
        commit(0);
        __syncthreads();
      }
    }

    // ---- in-register 2x2 attention + residual + store (wave-local) ----
    // C/D layout: col = t*16 + m (W feature), row = qg*4 + rr (x row within wave)
    {
      const size_t er0 = (size_t)blockIdx.x * BM + wave * 16 + qg * 4;
      const float* xp = x + er0 * D + (size_t)h * 64 + m;
      float*       op = out + er0 * D + (size_t)h * 64 + m;
      const float scale = 0.17677669529663687f;  // 1/sqrt(32)
#pragma unroll
      for (int rr = 0; rr < 4; ++rr) {
        // q: frags 0-3 (cols 0-63), k: 4-7, v: 8-11
        float s00 = acc[0][rr]*acc[4][rr] + acc[1][rr]*acc[5][rr];
        float s01 = acc[0][rr]*acc[6][rr] + acc[1][rr]*acc[7][rr];
        float s10 = acc[2][rr]*acc[4][rr] + acc[3][rr]*acc[5][rr];
        float s11 = acc[2][rr]*acc[6][rr] + acc[3][rr]*acc[7][rr];
#pragma unroll
        for (int d2 = 1; d2 <= 8; d2 <<= 1) {
          s00 += __shfl_xor(s00, d2, 64);
          s01 += __shfl_xor(s01, d2, 64);
          s10 += __shfl_xor(s10, d2, 64);
          s11 += __shfl_xor(s11, d2, 64);
        }
        s00 *= scale; s01 *= scale; s10 *= scale; s11 *= scale;
        float mx0 = fmaxf(s00, s01);
        float e00 = __expf(s00 - mx0), e01 = __expf(s01 - mx0);
        float r0 = 1.0f / (e00 + e01);
        float a00 = e00 * r0, a01 = e01 * r0;
        float mx1 = fmaxf(s10, s11);
        float e10 = __expf(s10 - mx1), e11 = __expf(s11 - mx1);
        float r1 = 1.0f / (e10 + e11);
        float a10 = e10 * r1, a11 = e11 * r1;

        const float* xq = xp + (size_t)rr * D;
        float*       oq = op + (size_t)rr * D;
        // out col = h*64 + p*32 + dk; lane m covers dk in {m, 16+m}
        oq[0]  = a00 * acc[8][rr]  + a01 * acc[10][rr] + xq[0];   // p0, dk=m
        oq[16] = a00 * acc[9][rr]  + a01 * acc[11][rr] + xq[16];  // p0, dk=16+m
        oq[32] = a10 * acc[8][rr]  + a11 * acc[10][rr] + xq[32];  // p1, dk=m
        oq[48] = a10 * acc[9][rr]  + a11 * acc[11][rr] + xq[48];  // p1, dk=16+m
      }
    }
  }
}

extern "C" void kernel_launch(void* const* d_in, const int* in_sizes, int n_in,
                              void* d_out, int out_size, void* d_ws, size_t ws_size,
                              hipStream_t stream) {
  const float* x     = (const float*)d_in[0];
  const float* Wq    = (const float*)d_in[1];
  const float* Wk    = (const float*)d_in[2];
  const float* Wv    = (const float*)d_in[3];
  const float* gamma = (const float*)d_in[4];
  const float* beta  = (const float*)d_in[5];
  float* out = (float*)d_out;
  (void)d_ws; (void)ws_size; (void)in_sizes; (void)n_in; (void)out_size;

  fused_kernel<<<dim3(BS / BM), dim3(512), 0, stream>>>(x, Wq, Wk, Wv, gamma, beta, out);
}

// Round 2
// 772.395 us; speedup vs baseline: 1.3431x; 1.0782x over previous
//
#include <hip/hip_runtime.h>

typedef _Float16 f16;
typedef _Float16 f16x8 __attribute__((ext_vector_type(8)));
typedef float f32x16 __attribute__((ext_vector_type(16)));

#define BS 65536
#define D 768
#define H 12
#define NBLK ((BS / 128) * H)   // 6144 main blocks
#define W_ELEMS ((size_t)D * D)
#define XN_ELEMS ((size_t)BS * D)

typedef const __attribute__((address_space(1))) void gvoid_t;
typedef __attribute__((address_space(3))) void lvoid_t;

// ---------------- prepass 1: LayerNorm -> xn (f16, gamma/beta folded in) ----------------
__global__ __launch_bounds__(256, 4) void ln_kernel(const float* __restrict__ x,
                                                    const float* __restrict__ gamma,
                                                    const float* __restrict__ beta,
                                                    f16* __restrict__ xn) {
  int tid = threadIdx.x;
  int r   = tid >> 2;   // 0..63
  int sub = tid & 3;
  size_t row = (size_t)blockIdx.x * 64 + r;
  const float4* xr4 = (const float4*)(x + row * D) + sub * 48;
  float sum = 0.f, sq = 0.f;
#pragma unroll 8
  for (int j = 0; j < 48; ++j) {
    float4 w = xr4[j];
    sum += w.x + w.y + w.z + w.w;
    sq  += w.x * w.x + w.y * w.y + w.z * w.z + w.w * w.w;
  }
  sum += __shfl_xor(sum, 1, 64); sum += __shfl_xor(sum, 2, 64);
  sq  += __shfl_xor(sq,  1, 64); sq  += __shfl_xor(sq,  2, 64);
  float mu   = sum * (1.0f / D);
  float rstd = rsqrtf(sq * (1.0f / D) - mu * mu + 1e-6f);
  // force reload of x (don't keep 48 float4 live across the shuffles)
  asm volatile("" ::: "memory");
  const float4* g4 = (const float4*)(gamma) + sub * 48;
  const float4* b4 = (const float4*)(beta)  + sub * 48;
  f16* xo = xn + row * D + sub * 192;
#pragma unroll 4
  for (int j = 0; j < 24; ++j) {
    float4 v0 = xr4[2 * j], v1 = xr4[2 * j + 1];
    float4 g0 = g4[2 * j],  g1 = g4[2 * j + 1];
    float4 b0 = b4[2 * j],  b1 = b4[2 * j + 1];
    f16x8 o;
    o[0] = (f16)((v0.x - mu) * rstd * g0.x + b0.x);
    o[1] = (f16)((v0.y - mu) * rstd * g0.y + b0.y);
    o[2] = (f16)((v0.z - mu) * rstd * g0.z + b0.z);
    o[3] = (f16)((v0.w - mu) * rstd * g0.w + b0.w);
    o[4] = (f16)((v1.x - mu) * rstd * g1.x + b1.x);
    o[5] = (f16)((v1.y - mu) * rstd * g1.y + b1.y);
    o[6] = (f16)((v1.z - mu) * rstd * g1.z + b1.z);
    o[7] = (f16)((v1.w - mu) * rstd * g1.w + b1.w);
    *(f16x8*)(xo + j * 8) = o;
  }
}

// ---------------- prepass 2: W f32 -> f16 (enables global_load_lds staging) ----------------
__global__ __launch_bounds__(256, 4) void wconv_kernel(const float* __restrict__ Wq,
                                                       const float* __restrict__ Wk,
                                                       const float* __restrict__ Wv,
                                                       f16* __restrict__ wf) {
  int b = blockIdx.x;          // 0..863 (3 * 288)
  int m = b / 288;
  size_t e = ((size_t)(b % 288) * 256 + threadIdx.x) * 8;
  const float* src = (m == 0 ? Wq : (m == 1 ? Wk : Wv)) + e;
  float4 v0 = *(const float4*)src;
  float4 v1 = *(const float4*)(src + 4);
  f16x8 o;
  o[0] = (f16)v0.x; o[1] = (f16)v0.y; o[2] = (f16)v0.z; o[3] = (f16)v0.w;
  o[4] = (f16)v1.x; o[5] = (f16)v1.y; o[6] = (f16)v1.z; o[7] = (f16)v1.w;
  *(f16x8*)(wf + (size_t)m * W_ELEMS + e) = o;
}

// ---------------- main: QKV GEMM (32x32x16 MFMA) + 2x2 attention + residual ----------------
// Block (rb, h): 128 rows x 192 cols (q|k|v for head h), K = 768. 256 threads = 4 waves,
// wave w owns rows w*32..+32 (A from global xn, straight into A-frags: row = lane&31,
// k = (lane>>5)*8 + j). B: 192x64 f16 LDS tile, double-buffered, staged via
// global_load_lds with pre-swizzled GLOBAL source: LDS chunk (row r, slot sc) holds
// global k-chunk cc = sc ^ (r&7)  ->  ds_read_b128 of a column slice is bank-optimal.
__global__ __launch_bounds__(256, 2) void qkv_attn_kernel(const f16* __restrict__ xn,
                                                          const f16* __restrict__ wf,
                                                          const float* __restrict__ x,
                                                          float* __restrict__ out) {
  __shared__ f16 sB[2][192 * 64] __attribute__((aligned(16)));

  const int tid  = threadIdx.x;
  const int wave = tid >> 6;
  const int lane = tid & 63;
  const int l31  = lane & 31;
  const int hi   = lane >> 5;

  // XCD-bijective swizzle: 6144 % 8 == 0; each XCD gets 64 contiguous rb-groups (x L2 reuse)
  int bid = blockIdx.x;
  int my  = (bid & 7) * (NBLK / 8) + (bid >> 3);
  int rb  = my / H;
  int h   = my % H;

  // ---- staging: per wave 6 global_load_lds ops per K-step; op o covers rows
  // r = wave*48 + o*8 + (lane>>3), lane's LDS slot sc = lane&7 -> global chunk cc = sc ^ (r&7)
  unsigned offs[6];  // f16-elem offsets into wf (ko term added per step)
  {
    int rl = wave * 48 + (lane >> 3);
#pragma unroll
    for (int o = 0; o < 6; ++o) {
      int r  = rl + o * 8;
      int cc = (lane & 7) ^ ((lane >> 3) & 7);   // r&7 == (lane>>3)&7 (rowbase % 8 == 0)
      offs[o] = (unsigned)((r >> 6) * (int)W_ELEMS + ((h * 64 + (r & 63)) * D) + cc * 8);
    }
  }

  // B-frag read offsets: row n = t*32 + l31, slot = (s*2+hi) ^ (n&7); n stride = 64 elems
  const int rowb = l31 * 64;
  int coff[4];
#pragma unroll
  for (int s = 0; s < 4; ++s) coff[s] = ((s * 2 + hi) ^ (l31 & 7)) * 8;

  // A pointer: row = rb*128 + wave*32 + l31, k-octet = hi*8
  const f16* ap = xn + ((size_t)rb * 128 + wave * 32 + l31) * D + hi * 8;

#define STAGE(KO, BUF)                                                                  \
  {                                                                                     \
    const f16* bp = wf + (KO) * 64;                                                     \
    _Pragma("unroll") for (int o = 0; o < 6; ++o) {                                     \
      __builtin_amdgcn_global_load_lds((gvoid_t*)(bp + offs[o]),                        \
                                       (lvoid_t*)(&sB[BUF][wave * 3072 + o * 512]),     \
                                       16, 0, 0);                                       \
    }                                                                                   \
  }

  STAGE(0, 0);

  f32x16 acc[6];
#pragma unroll
  for (int t = 0; t < 6; ++t)
#pragma unroll
    for (int i = 0; i < 16; ++i) acc[t][i] = 0.f;

  __syncthreads();  // drains stage(0)

#pragma unroll
  for (int ko = 0; ko < 12; ++ko) {
    const int cur = ko & 1;
    if (ko < 11) STAGE(ko + 1, cur ^ 1);
    __builtin_amdgcn_sched_barrier(0);  // keep next-tile issue above the MFMAs

    const f16* bb = &sB[cur][rowb];
    __builtin_amdgcn_s_setprio(1);
#pragma unroll
    for (int s = 0; s < 4; ++s) {
      f16x8 as = *(const f16x8*)(ap + ko * 64 + s * 16);
#pragma unroll
      for (int t = 0; t < 6; ++t) {
        f16x8 b = *(const f16x8*)(bb + coff[s] + t * 2048);
        acc[t] = __builtin_amdgcn_mfma_f32_32x32x16_f16(as, b, acc[t], 0, 0, 0);
      }
    }
    __builtin_amdgcn_s_setprio(0);
    if (ko < 11) __syncthreads();
  }

  // ---- epilogue: 2x2 attention per row, in-register ----
  // C/D: col = t*32 + l31, row-in-wave = (g&3) + 8*(g>>2) + 4*hi
  // t: 0=q_p0 1=q_p1 2=k_p0 3=k_p1 4=v_p0 5=v_p1 ; dk = l31
  {
    const size_t grow0 = (size_t)rb * 128 + wave * 32;
    const float scale = 0.17677669529663687f;  // 1/sqrt(32)
#pragma unroll
    for (int g = 0; g < 16; ++g) {
      float q0 = acc[0][g], q1 = acc[1][g];
      float k0 = acc[2][g], k1 = acc[3][g];
      float s00 = q0 * k0, s01 = q0 * k1, s10 = q1 * k0, s11 = q1 * k1;
#pragma unroll
      for (int d2 = 1; d2 <= 16; d2 <<= 1) {
        s00 += __shfl_xor(s00, d2, 64);
        s01 += __shfl_xor(s01, d2, 64);
        s10 += __shfl_xor(s10, d2, 64);
        s11 += __shfl_xor(s11, d2, 64);
      }
      s00 *= scale; s01 *= scale; s10 *= scale; s11 *= scale;
      float mx0 = fmaxf(s00, s01);
      float e00 = __expf(s00 - mx0), e01 = __expf(s01 - mx0);
      float r0 = 1.0f / (e00 + e01);
      float a00 = e00 * r0, a01 = e01 * r0;
      float mx1 = fmaxf(s10, s11);
      float e10 = __expf(s10 - mx1), e11 = __expf(s11 - mx1);
      float r1 = 1.0f / (e10 + e11);
      float a10 = e10 * r1, a11 = e11 * r1;

      int row_w = (g & 3) + 8 * (g >> 2) + 4 * hi;
      const float* xp = x   + (grow0 + row_w) * D + h * 64 + l31;
      float*       op = out + (grow0 + row_w) * D + h * 64 + l31;
      float v0 = acc[4][g], v1 = acc[5][g];
      op[0]  = a00 * v0 + a01 * v1 + xp[0];    // p0: col h*64 + dk
      op[32] = a10 * v0 + a11 * v1 + xp[32];   // p1: col h*64 + 32 + dk
    }
  }
#undef STAGE
}

extern "C" void kernel_launch(void* const* d_in, const int* in_sizes, int n_in,
                              void* d_out, int out_size, void* d_ws, size_t ws_size,
                              hipStream_t stream) {
  const float* x     = (const float*)d_in[0];
  const float* Wq    = (const float*)d_in[1];
  const float* Wk    = (const float*)d_in[2];
  const float* Wv    = (const float*)d_in[3];
  const float* gamma = (const float*)d_in[4];
  const float* beta  = (const float*)d_in[5];
  float* out = (float*)d_out;
  (void)in_sizes; (void)n_in; (void)out_size; (void)ws_size;

  f16* xn = (f16*)d_ws;                 // 100.7 MB
  f16* wf = xn + XN_ELEMS;              // + 3.5 MB  (needs ws_size >= ~104.3 MB)

  ln_kernel<<<dim3(BS / 64), dim3(256), 0, stream>>>(x, gamma, beta, xn);
  wconv_kernel<<<dim3(864), dim3(256), 0, stream>>>(Wq, Wk, Wv, wf);
  qkv_attn_kernel<<<dim3(NBLK), dim3(256), 0, stream>>>(xn, wf, x, out);
}

// Round 3
// 712.605 us; speedup vs baseline: 1.4558x; 1.0839x over previous
//
#include <hip/hip_runtime.h>

typedef _Float16 f16;
typedef _Float16 f16x8 __attribute__((ext_vector_type(8)));
typedef _Float16 f16x4 __attribute__((ext_vector_type(4)));
typedef float f32x16 __attribute__((ext_vector_type(16)));

#define BS 65536
#define D 768
#define H 12
#define RB 256                   // rows per main block
#define NBLK ((BS / RB) * H)     // 3072
#define W_ELEMS ((size_t)D * D)
#define XN_ELEMS ((size_t)BS * D)

typedef const __attribute__((address_space(1))) void gvoid_t;
typedef __attribute__((address_space(3))) void lvoid_t;

// ---------------- prepass 1: LayerNorm -> xn (f16, gamma/beta folded), single pass ----------------
// One wave per row; lane holds 12 contiguous f32 in registers (x read exactly once).
__global__ __launch_bounds__(256, 4) void ln_kernel(const float* __restrict__ x,
                                                    const float* __restrict__ gamma,
                                                    const float* __restrict__ beta,
                                                    f16* __restrict__ xn) {
  int wave = threadIdx.x >> 6, lane = threadIdx.x & 63;
  size_t row = (size_t)blockIdx.x * 4 + wave;
  const float4* xr = (const float4*)(x + row * D) + lane * 3;
  float4 v0 = xr[0], v1 = xr[1], v2 = xr[2];
  float sum = (v0.x + v0.y) + (v0.z + v0.w) + (v1.x + v1.y) + (v1.z + v1.w)
            + (v2.x + v2.y) + (v2.z + v2.w);
  float sq = v0.x*v0.x + v0.y*v0.y + v0.z*v0.z + v0.w*v0.w
           + v1.x*v1.x + v1.y*v1.y + v1.z*v1.z + v1.w*v1.w
           + v2.x*v2.x + v2.y*v2.y + v2.z*v2.z + v2.w*v2.w;
#pragma unroll
  for (int d2 = 1; d2 <= 32; d2 <<= 1) {
    sum += __shfl_xor(sum, d2, 64);
    sq  += __shfl_xor(sq,  d2, 64);
  }
  float mu   = sum * (1.0f / D);
  float rstd = rsqrtf(sq * (1.0f / D) - mu * mu + 1e-6f);
  const float4* g4 = (const float4*)(gamma) + lane * 3;
  const float4* b4 = (const float4*)(beta)  + lane * 3;
  float4 g0 = g4[0], g1 = g4[1], g2 = g4[2];
  float4 b0 = b4[0], b1 = b4[1], b2 = b4[2];
  f16* xo = xn + row * D + lane * 12;
  f16x4 o0, o1, o2;
  o0[0] = (f16)((v0.x - mu) * rstd * g0.x + b0.x);
  o0[1] = (f16)((v0.y - mu) * rstd * g0.y + b0.y);
  o0[2] = (f16)((v0.z - mu) * rstd * g0.z + b0.z);
  o0[3] = (f16)((v0.w - mu) * rstd * g0.w + b0.w);
  o1[0] = (f16)((v1.x - mu) * rstd * g1.x + b1.x);
  o1[1] = (f16)((v1.y - mu) * rstd * g1.y + b1.y);
  o1[2] = (f16)((v1.z - mu) * rstd * g1.z + b1.z);
  o1[3] = (f16)((v1.w - mu) * rstd * g1.w + b1.w);
  o2[0] = (f16)((v2.x - mu) * rstd * g2.x + b2.x);
  o2[1] = (f16)((v2.y - mu) * rstd * g2.y + b2.y);
  o2[2] = (f16)((v2.z - mu) * rstd * g2.z + b2.z);
  o2[3] = (f16)((v2.w - mu) * rstd * g2.w + b2.w);
  *(f16x4*)(xo)     = o0;
  *(f16x4*)(xo + 4) = o1;
  *(f16x4*)(xo + 8) = o2;
}

// ---------------- prepass 2: W f32 -> f16 ----------------
__global__ __launch_bounds__(256, 4) void wconv_kernel(const float* __restrict__ Wq,
                                                       const float* __restrict__ Wk,
                                                       const float* __restrict__ Wv,
                                                       f16* __restrict__ wf) {
  int b = blockIdx.x;          // 0..863 (3 * 288)
  int m = b / 288;
  size_t e = ((size_t)(b % 288) * 256 + threadIdx.x) * 8;
  const float* src = (m == 0 ? Wq : (m == 1 ? Wk : Wv)) + e;
  float4 v0 = *(const float4*)src;
  float4 v1 = *(const float4*)(src + 4);
  f16x8 o;
  o[0] = (f16)v0.x; o[1] = (f16)v0.y; o[2] = (f16)v0.z; o[3] = (f16)v0.w;
  o[4] = (f16)v1.x; o[5] = (f16)v1.y; o[6] = (f16)v1.z; o[7] = (f16)v1.w;
  *(f16x8*)(wf + (size_t)m * W_ELEMS + e) = o;
}

// ---------------- main: QKV GEMM (32x32x16) + 2x2 attention + residual ----------------
// Block (rb,h): 256 rows x 192 cols, K=768. 4 waves, wave owns 64 rows (2 row-tiles) ->
// each B-fragment feeds 2 MFMAs (halved LDS traffic per FLOP vs 32 rows/wave).
// B tile 192x64 f16, double-buffered, staged via global_load_lds; LDS layout is
// conflict-free BY CONSTRUCTION (no xor swizzle):
//   stage op = 8 rows x 8 chunks, lane = c*8 + r  ->  chunk(r,c) @ (r>>3)*1024 + c*128 + (r&7)*16
//   B-frag read: every 8-lane group reads 128 CONTIGUOUS bytes -> 8-pass minimum, 0 conflicts.
__global__ __launch_bounds__(256, 2) void qkv_attn_kernel(const f16* __restrict__ xn,
                                                          const f16* __restrict__ wf,
                                                          const float* __restrict__ x,
                                                          float* __restrict__ out) {
  __shared__ f16 sB[2][192 * 64] __attribute__((aligned(16)));

  const int tid  = threadIdx.x;
  const int wave = tid >> 6;
  const int lane = tid & 63;
  const int l31  = lane & 31;
  const int hi   = lane >> 5;

  // XCD-bijective swizzle: 3072 % 8 == 0; 12 head-blocks of one rb land adjacent (xn L2 reuse)
  int bid = blockIdx.x;
  int my  = (bid & 7) * (NBLK / 8) + (bid >> 3);
  int rb  = my / H;
  int h   = my % H;

  // staging: wave w, op o: tile rows r = w*48 + o*8 + (lane&7), k-chunk c = lane>>3
  unsigned offs[6];
  {
    int rl = wave * 48 + (lane & 7);
    int c  = lane >> 3;
#pragma unroll
    for (int o = 0; o < 6; ++o) {
      int r = rl + o * 8;
      offs[o] = (unsigned)((r >> 6) * (int)W_ELEMS + (h * 64 + (r & 63)) * D + c * 8);
    }
  }

  // B-frag read: elem = (t*4 + (l31>>3))*512 + (s*2+hi)*64 + (l31&7)*8
  const int rbase = (l31 >> 3) * 512 + hi * 64 + (l31 & 7) * 8;

  // A: row = rb*256 + wave*64 + rt*32 + l31, k = ko*64 + s*16 + hi*8
  const f16* ap0 = xn + ((size_t)rb * RB + wave * 64 + l31) * D + hi * 8;
  const f16* ap1 = ap0 + (size_t)32 * D;

#define STAGE(KO, BUF)                                                                   \
  {                                                                                      \
    const f16* bp = wf + (KO) * 64;                                                      \
    _Pragma("unroll") for (int o = 0; o < 6; ++o) {                                      \
      __builtin_amdgcn_global_load_lds((gvoid_t*)(bp + offs[o]),                         \
                                       (lvoid_t*)(&sB[BUF][(wave * 6 + o) * 512]),       \
                                       16, 0, 0);                                        \
    }                                                                                    \
  }

  STAGE(0, 0);

  f32x16 acc[6][2];
#pragma unroll
  for (int t = 0; t < 6; ++t)
#pragma unroll
    for (int rt = 0; rt < 2; ++rt)
#pragma unroll
      for (int i = 0; i < 16; ++i) acc[t][rt][i] = 0.f;

  __syncthreads();  // drains stage(0)

#pragma unroll
  for (int ko = 0; ko < 12; ++ko) {
    const int cur = ko & 1;
    if (ko < 11) STAGE(ko + 1, cur ^ 1);
    __builtin_amdgcn_sched_barrier(0);  // keep next-tile issue above the MFMAs

    const f16* bb = &sB[cur][rbase];
    __builtin_amdgcn_s_setprio(1);
#pragma unroll
    for (int s = 0; s < 4; ++s) {
      f16x8 a0 = *(const f16x8*)(ap0 + ko * 64 + s * 16);
      f16x8 a1 = *(const f16x8*)(ap1 + ko * 64 + s * 16);
#pragma unroll
      for (int t = 0; t < 6; ++t) {
        f16x8 b = *(const f16x8*)(bb + t * 2048 + s * 128);
        acc[t][0] = __builtin_amdgcn_mfma_f32_32x32x16_f16(a0, b, acc[t][0], 0, 0, 0);
        acc[t][1] = __builtin_amdgcn_mfma_f32_32x32x16_f16(a1, b, acc[t][1], 0, 0, 0);
      }
    }
    __builtin_amdgcn_s_setprio(0);
    if (ko < 11) __syncthreads();
  }

  // ---- epilogue: 2x2 attention per row, in-register ----
  // C/D: col = t*32 + l31, row-in-wave = (g&3) + 8*(g>>2) + 4*hi
  // t: 0=q_p0 1=q_p1 2=k_p0 3=k_p1 4=v_p0 5=v_p1 ; dk = l31
  {
    const float scale = 0.17677669529663687f;  // 1/sqrt(32)
#pragma unroll
    for (int rt = 0; rt < 2; ++rt) {
      const size_t grow0 = (size_t)rb * RB + wave * 64 + rt * 32;
#pragma unroll
      for (int g = 0; g < 16; ++g) {
        float q0 = acc[0][rt][g], q1 = acc[1][rt][g];
        float k0 = acc[2][rt][g], k1 = acc[3][rt][g];
        float s00 = q0 * k0, s01 = q0 * k1, s10 = q1 * k0, s11 = q1 * k1;
#pragma unroll
        for (int d2 = 1; d2 <= 16; d2 <<= 1) {
          s00 += __shfl_xor(s00, d2, 64);
          s01 += __shfl_xor(s01, d2, 64);
          s10 += __shfl_xor(s10, d2, 64);
          s11 += __shfl_xor(s11, d2, 64);
        }
        s00 *= scale; s01 *= scale; s10 *= scale; s11 *= scale;
        float mx0 = fmaxf(s00, s01);
        float e00 = __expf(s00 - mx0), e01 = __expf(s01 - mx0);
        float r0 = 1.0f / (e00 + e01);
        float a00 = e00 * r0, a01 = e01 * r0;
        float mx1 = fmaxf(s10, s11);
        float e10 = __expf(s10 - mx1), e11 = __expf(s11 - mx1);
        float r1 = 1.0f / (e10 + e11);
        float a10 = e10 * r1, a11 = e11 * r1;

        int row_w = (g & 3) + 8 * (g >> 2) + 4 * hi;
        const float* xp = x   + (grow0 + row_w) * D + h * 64 + l31;
        float*       op = out + (grow0 + row_w) * D + h * 64 + l31;
        float v0 = acc[4][rt][g], v1 = acc[5][rt][g];
        op[0]  = a00 * v0 + a01 * v1 + xp[0];    // p0: col h*64 + dk
        op[32] = a10 * v0 + a11 * v1 + xp[32];   // p1: col h*64 + 32 + dk
      }
    }
  }
#undef STAGE
}

extern "C" void kernel_launch(void* const* d_in, const int* in_sizes, int n_in,
                              void* d_out, int out_size, void* d_ws, size_t ws_size,
                              hipStream_t stream) {
  const float* x     = (const float*)d_in[0];
  const float* Wq    = (const float*)d_in[1];
  const float* Wk    = (const float*)d_in[2];
  const float* Wv    = (const float*)d_in[3];
  const float* gamma = (const float*)d_in[4];
  const float* beta  = (const float*)d_in[5];
  float* out = (float*)d_out;
  (void)in_sizes; (void)n_in; (void)out_size; (void)ws_size;

  f16* xn = (f16*)d_ws;                 // 100.7 MB
  f16* wf = xn + XN_ELEMS;              // + 3.5 MB  (needs ws_size >= ~104.3 MB)

  ln_kernel<<<dim3(BS / 4), dim3(256), 0, stream>>>(x, gamma, beta, xn);
  wconv_kernel<<<dim3(864), dim3(256), 0, stream>>>(Wq, Wk, Wv, wf);
  qkv_attn_kernel<<<dim3(NBLK), dim3(256), 0, stream>>>(xn, wf, x, out);
}